// Round 3
// baseline (20580.743 us; speedup 1.0000x reference)
//
#include <hip/hip_runtime.h>
#include <hip/hip_cooperative_groups.h>
#include <cstdint>
#include <cmath>

namespace cg = cooperative_groups;

// ---------------------------------------------------------------------------
// SelectiveWhElmanCell — round 3.
//  1) threefry RNG + 3-step power iteration -> scale (unchanged).
//  2) fused dual GEMM 128x128/8x8 (unchanged).
//  3) persistent cooperative recurrence, resource-light version:
//     256 blocks x 512 threads (8 waves/CU, 2/SIMD). Block owns 8 columns.
//     Thread (c = tid&7, ks = tid>>3) holds W_h[e0+c][ks*32..+32) in
//     registers (scaled once). Per step it accumulates partial dots for all
//     64 batch rows in 4 groups of 16; partials are reduced across the 8
//     ks-slices of each wave by a 3-step __shfl_xor reduce-scatter
//     (compile-time register indices only), leaving just 8 wave-level
//     partials per (row,col) to combine through an 18.4 KB LDS scratch.
//     Tail (tanh/silu) applied by the (r,c)-owner thread. grid.sync()/step.
//  Fallback: if the cooperative config cannot be co-resident (occupancy
//  query) or the launch errors, run the proven per-step k_step path.
// ---------------------------------------------------------------------------

static constexpr int Tt = 256;
static constexpr int Bb = 64;
static constexpr int Dk = 2048;
static constexpr int Mrows = Tt * Bb;          // 16384
static constexpr float EPSF = 1e-8f;
static constexpr float TARGET_RADIUS = 0.99f;

// ------------------------------ threefry -----------------------------------
__device__ __forceinline__ void tf_round(uint32_t& x0, uint32_t& x1, int r) {
    x0 += x1;
    x1 = (x1 << r) | (x1 >> (32 - r));
    x1 ^= x0;
}

__device__ __forceinline__ uint2 threefry2x32(uint32_t ks0, uint32_t ks1,
                                              uint32_t x0, uint32_t x1) {
    uint32_t ks2 = ks0 ^ ks1 ^ 0x1BD11BDAu;
    x0 += ks0; x1 += ks1;
    tf_round(x0,x1,13); tf_round(x0,x1,15); tf_round(x0,x1,26); tf_round(x0,x1,6);
    x0 += ks1; x1 += ks2 + 1u;
    tf_round(x0,x1,17); tf_round(x0,x1,29); tf_round(x0,x1,16); tf_round(x0,x1,24);
    x0 += ks2; x1 += ks0 + 2u;
    tf_round(x0,x1,13); tf_round(x0,x1,15); tf_round(x0,x1,26); tf_round(x0,x1,6);
    x0 += ks0; x1 += ks1 + 3u;
    tf_round(x0,x1,17); tf_round(x0,x1,29); tf_round(x0,x1,16); tf_round(x0,x1,24);
    x0 += ks1; x1 += ks2 + 4u;
    tf_round(x0,x1,13); tf_round(x0,x1,15); tf_round(x0,x1,26); tf_round(x0,x1,6);
    x0 += ks2; x1 += ks0 + 5u;
    return make_uint2(x0, x1);
}

// u0 = normal(key(42), (2048,)); u0 /= ||u0||  (no eps on first normalize).
__global__ __launch_bounds__(256) void k_rng(float* __restrict__ u) {
    __shared__ float red[256];
    __shared__ float s_inv;
    float local = 0.f;
    for (int i = threadIdx.x; i < Dk; i += 256) {
        uint2 r = threefry2x32(0u, 42u, 0u, (uint32_t)i);
        uint32_t bits = r.x ^ r.y;
        uint32_t fb = (bits >> 9) | 0x3f800000u;
        float f01 = __uint_as_float(fb) - 1.0f;           // [0,1)
        const float lo = -0.99999994f;                    // nextafter(-1,0)
        float uu = f01 * (1.0f - lo) + lo;
        uu = fmaxf(lo, uu);
        float g = 1.41421356237f * erfinvf(uu);
        u[i] = g;
        local += g * g;
    }
    red[threadIdx.x] = local;
    __syncthreads();
    for (int s = 128; s > 0; s >>= 1) {
        if (threadIdx.x < s) red[threadIdx.x] += red[threadIdx.x + s];
        __syncthreads();
    }
    if (threadIdx.x == 0) s_inv = 1.0f / sqrtf(red[0]);
    __syncthreads();
    float inv = s_inv;
    for (int i = threadIdx.x; i < Dk; i += 256) u[i] *= inv;
}

// out[j] = sum_i W[i,j] * u[i]   (W^T @ u)
__global__ __launch_bounds__(256) void k_matvec_T(const float* __restrict__ W,
                                                  const float* __restrict__ u,
                                                  float* __restrict__ out) {
    __shared__ float us[Dk];
    for (int i = threadIdx.x; i < Dk; i += 256) us[i] = u[i];
    __syncthreads();
    int j = blockIdx.x * 256 + threadIdx.x;
    float acc = 0.f;
    for (int i = 0; i < Dk; ++i) acc += W[(size_t)i * Dk + j] * us[i];
    out[j] = acc;
}

// out[row] = sum_j W[row,j] * v[j]   (W @ v), one block per row
__global__ __launch_bounds__(256) void k_matvec_N(const float* __restrict__ W,
                                                  const float* __restrict__ v,
                                                  float* __restrict__ out) {
    __shared__ float red[256];
    const float* Wr = W + (size_t)blockIdx.x * Dk;
    float acc = 0.f;
    for (int j = threadIdx.x; j < Dk; j += 256) acc += Wr[j] * v[j];
    red[threadIdx.x] = acc;
    __syncthreads();
    for (int s = 128; s > 0; s >>= 1) {
        if (threadIdx.x < s) red[threadIdx.x] += red[threadIdx.x + s];
        __syncthreads();
    }
    if (threadIdx.x == 0) out[blockIdx.x] = red[0];
}

// vec /= (||vec|| + eps)
__global__ __launch_bounds__(256) void k_normalize(float* __restrict__ vec) {
    __shared__ float red[256];
    __shared__ float s_inv;
    float acc = 0.f;
    for (int i = threadIdx.x; i < Dk; i += 256) { float x = vec[i]; acc += x * x; }
    red[threadIdx.x] = acc;
    __syncthreads();
    for (int s = 128; s > 0; s >>= 1) {
        if (threadIdx.x < s) red[threadIdx.x] += red[threadIdx.x + s];
        __syncthreads();
    }
    if (threadIdx.x == 0) s_inv = 1.0f / (sqrtf(red[0]) + EPSF);
    __syncthreads();
    float inv = s_inv;
    for (int i = threadIdx.x; i < Dk; i += 256) vec[i] *= inv;
}

// sigma = ||uraw||^2/(||uraw||+eps); scale = 0.99/(sigma+eps)
__global__ __launch_bounds__(256) void k_sigma(const float* __restrict__ uraw,
                                               float* __restrict__ scale_out) {
    __shared__ float red[256];
    float acc = 0.f;
    for (int i = threadIdx.x; i < Dk; i += 256) { float x = uraw[i]; acc += x * x; }
    red[threadIdx.x] = acc;
    __syncthreads();
    for (int s = 128; s > 0; s >>= 1) {
        if (threadIdx.x < s) red[threadIdx.x] += red[threadIdx.x + s];
        __syncthreads();
    }
    if (threadIdx.x == 0) {
        float ss = red[0];
        float n = sqrtf(ss);
        float sigma = ss / (n + EPSF);
        scale_out[0] = TARGET_RADIUS / (sigma + EPSF);
    }
}

// --------------------------- fused dual GEMM -------------------------------
// BM=BN=128, BK=16, 256 threads, 8x8 micro-tile, dual accumulators.
__global__ __launch_bounds__(256, 2) void k_dualgemm(const float* __restrict__ X,
                                                     const float* __restrict__ Wx,
                                                     const float* __restrict__ Wg,
                                                     const float* __restrict__ bias,
                                                     float* __restrict__ xw_out,
                                                     float* __restrict__ gate_out) {
    __shared__ float As [16][132];
    __shared__ float Bxs[16][132];
    __shared__ float Bgs[16][132];

    const int tid = threadIdx.x;
    const int bm = blockIdx.x;
    const int bn = blockIdx.y;
    const int tx = tid & 15;
    const int ty = tid >> 4;

    float accX[8][8] = {};
    float accG[8][8] = {};

    const int lrow = tid >> 2;
    const int lk4  = (tid & 3) << 2;
    const float* Xp0  = X  + (size_t)(bm * 128 + lrow) * Dk + lk4;
    const float* Xp1  = Xp0 + (size_t)64 * Dk;
    const float* Wxp0 = Wx + (size_t)(bn * 128 + lrow) * Dk + lk4;
    const float* Wxp1 = Wxp0 + (size_t)64 * Dk;
    const float* Wgp0 = Wg + (size_t)(bn * 128 + lrow) * Dk + lk4;
    const float* Wgp1 = Wgp0 + (size_t)64 * Dk;

    for (int k0 = 0; k0 < Dk; k0 += 16) {
        float4 xa0 = *(const float4*)(Xp0  + k0);
        float4 xa1 = *(const float4*)(Xp1  + k0);
        float4 wx0 = *(const float4*)(Wxp0 + k0);
        float4 wx1 = *(const float4*)(Wxp1 + k0);
        float4 wg0 = *(const float4*)(Wgp0 + k0);
        float4 wg1 = *(const float4*)(Wgp1 + k0);
        __syncthreads();
        As [lk4 + 0][lrow]      = xa0.x; As [lk4 + 1][lrow]      = xa0.y;
        As [lk4 + 2][lrow]      = xa0.z; As [lk4 + 3][lrow]      = xa0.w;
        As [lk4 + 0][lrow + 64] = xa1.x; As [lk4 + 1][lrow + 64] = xa1.y;
        As [lk4 + 2][lrow + 64] = xa1.z; As [lk4 + 3][lrow + 64] = xa1.w;
        Bxs[lk4 + 0][lrow]      = wx0.x; Bxs[lk4 + 1][lrow]      = wx0.y;
        Bxs[lk4 + 2][lrow]      = wx0.z; Bxs[lk4 + 3][lrow]      = wx0.w;
        Bxs[lk4 + 0][lrow + 64] = wx1.x; Bxs[lk4 + 1][lrow + 64] = wx1.y;
        Bxs[lk4 + 2][lrow + 64] = wx1.z; Bxs[lk4 + 3][lrow + 64] = wx1.w;
        Bgs[lk4 + 0][lrow]      = wg0.x; Bgs[lk4 + 1][lrow]      = wg0.y;
        Bgs[lk4 + 2][lrow]      = wg0.z; Bgs[lk4 + 3][lrow]      = wg0.w;
        Bgs[lk4 + 0][lrow + 64] = wg1.x; Bgs[lk4 + 1][lrow + 64] = wg1.y;
        Bgs[lk4 + 2][lrow + 64] = wg1.z; Bgs[lk4 + 3][lrow + 64] = wg1.w;
        __syncthreads();
#pragma unroll
        for (int kk = 0; kk < 16; ++kk) {
            const float4 a0 = *(const float4*)&As [kk][ty * 8];
            const float4 a1 = *(const float4*)&As [kk][ty * 8 + 4];
            const float4 x0 = *(const float4*)&Bxs[kk][tx * 8];
            const float4 x1 = *(const float4*)&Bxs[kk][tx * 8 + 4];
            const float4 g0 = *(const float4*)&Bgs[kk][tx * 8];
            const float4 g1 = *(const float4*)&Bgs[kk][tx * 8 + 4];
            float av[8] = {a0.x, a0.y, a0.z, a0.w, a1.x, a1.y, a1.z, a1.w};
            float xv[8] = {x0.x, x0.y, x0.z, x0.w, x1.x, x1.y, x1.z, x1.w};
            float gv[8] = {g0.x, g0.y, g0.z, g0.w, g1.x, g1.y, g1.z, g1.w};
#pragma unroll
            for (int i = 0; i < 8; ++i)
#pragma unroll
                for (int j = 0; j < 8; ++j) {
                    accX[i][j] = fmaf(av[i], xv[j], accX[i][j]);
                    accG[i][j] = fmaf(av[i], gv[j], accG[i][j]);
                }
        }
    }

    const int m0 = bm * 128 + ty * 8;
    const int n0 = bn * 128 + tx * 8;
    float4 bv0 = *(const float4*)(bias + n0);
    float4 bv1 = *(const float4*)(bias + n0 + 4);
#pragma unroll
    for (int i = 0; i < 8; ++i) {
        float4 xo0, xo1, go0, go1;
        xo0.x = accX[i][0] + bv0.x; xo0.y = accX[i][1] + bv0.y;
        xo0.z = accX[i][2] + bv0.z; xo0.w = accX[i][3] + bv0.w;
        xo1.x = accX[i][4] + bv1.x; xo1.y = accX[i][5] + bv1.y;
        xo1.z = accX[i][6] + bv1.z; xo1.w = accX[i][7] + bv1.w;
        go0.x = 1.0f / (1.0f + expf(-accG[i][0]));
        go0.y = 1.0f / (1.0f + expf(-accG[i][1]));
        go0.z = 1.0f / (1.0f + expf(-accG[i][2]));
        go0.w = 1.0f / (1.0f + expf(-accG[i][3]));
        go1.x = 1.0f / (1.0f + expf(-accG[i][4]));
        go1.y = 1.0f / (1.0f + expf(-accG[i][5]));
        go1.z = 1.0f / (1.0f + expf(-accG[i][6]));
        go1.w = 1.0f / (1.0f + expf(-accG[i][7]));
        float* xrow = xw_out   + (size_t)(m0 + i) * Dk + n0;
        float* grow = gate_out + (size_t)(m0 + i) * Dk + n0;
        *(float4*)xrow       = xo0;
        *(float4*)(xrow + 4) = xo1;
        *(float4*)grow       = go0;
        *(float4*)(grow + 4) = go1;
    }
}

// ---------------------- per-step fallback (round-0, proven) ----------------
__global__ __launch_bounds__(256) void k_step(const float* __restrict__ Wh,
                                              const float* __restrict__ scale_p,
                                              const float* __restrict__ z_t,
                                              float* __restrict__ xw_t,
                                              const float* __restrict__ h_prev,
                                              float* __restrict__ hg_t) {
    __shared__ float Hs[32][36];
    __shared__ float Ws[32][36];
    const int tid = threadIdx.x;
    const int bn = blockIdx.x;
    const int bb = blockIdx.y;
    const int tx = tid & 15;
    const int ty = tid >> 4;

    float a00 = 0.f, a01 = 0.f, a10 = 0.f, a11 = 0.f;

    const int lrow = tid >> 3;
    const int lk4  = (tid & 7) * 4;
    const float* Hp = h_prev + (size_t)(bb * 32 + lrow) * Dk + lk4;
    const float* Wp = Wh     + (size_t)(bn * 32 + lrow) * Dk + lk4;

    for (int k0 = 0; k0 < Dk; k0 += 32) {
        float4 ha = *(const float4*)(Hp + k0);
        float4 wa = *(const float4*)(Wp + k0);
        __syncthreads();
        Hs[lk4 + 0][lrow] = ha.x; Hs[lk4 + 1][lrow] = ha.y;
        Hs[lk4 + 2][lrow] = ha.z; Hs[lk4 + 3][lrow] = ha.w;
        Ws[lk4 + 0][lrow] = wa.x; Ws[lk4 + 1][lrow] = wa.y;
        Ws[lk4 + 2][lrow] = wa.z; Ws[lk4 + 3][lrow] = wa.w;
        __syncthreads();
#pragma unroll
        for (int kk = 0; kk < 32; ++kk) {
            float2 hv = *(const float2*)&Hs[kk][ty * 2];
            float2 wv = *(const float2*)&Ws[kk][tx * 2];
            a00 += hv.x * wv.x; a01 += hv.x * wv.y;
            a10 += hv.y * wv.x; a11 += hv.y * wv.y;
        }
    }

    const float sc = scale_p[0];
    const int e0 = bn * 32 + tx * 2;
    const int b0 = bb * 32 + ty * 2;
    float acc[2][2] = {{a00, a01}, {a10, a11}};
#pragma unroll
    for (int i = 0; i < 2; ++i)
#pragma unroll
        for (int j = 0; j < 2; ++j) {
            size_t idx = (size_t)(b0 + i) * Dk + (e0 + j);
            float Rh = acc[i][j] * sc;
            float g = hg_t[idx];
            float pre = xw_t[idx] + Rh * g;
            float hn = tanhf(pre);
            float zv = z_t[idx];
            float sz = zv / (1.0f + expf(-zv));
            hg_t[idx] = hn;
            xw_t[idx] = hn * sz;
        }
}

// --------------------- persistent cooperative recurrence -------------------
// 256 blocks x 512 threads. Thread (c = tid&7, ks = tid>>3): W_h k-slice in
// regs; dot partials for 64 rows in 4 groups of 16; in-wave reduce-scatter
// over the 8 ks-slices of the wave; 8 wave-partials combined via 18.4 KB LDS.
__global__ __launch_bounds__(512, 2) void k_recur(const float* __restrict__ Wh,
                                                  const float* __restrict__ scale_p,
                                                  const float* __restrict__ z,
                                                  float* __restrict__ out,
                                                  float* __restrict__ hbuf) {
    cg::grid_group grid = cg::this_grid();
    __shared__ float red[8 * 576];     // 8 waves x 64 rows x (8+1 pad) = 18432 B

    const int tid = threadIdx.x;
    const int e0 = blockIdx.x * 8;
    const int c  = tid & 7;
    const int ks = tid >> 3;            // 0..63
    const int k0 = ks * 32;
    const int wv = tid >> 6;            // wave 0..7
    const float sc = scale_p[0];

    // W_h k-slice into registers, pre-scaled.
    float w[32];
    {
        const float* wp = Wh + (size_t)(e0 + c) * Dk + k0;
#pragma unroll
        for (int j = 0; j < 8; ++j) {
            float4 v = *(const float4*)(wp + 4 * j);
            w[4*j+0] = v.x * sc; w[4*j+1] = v.y * sc;
            w[4*j+2] = v.z * sc; w[4*j+3] = v.w * sc;
        }
    }

    // After the 3-step reduce-scatter, this lane holds rows
    // rr = 8*bit0(ksl) + 4*bit1(ksl) + 2*bit2(ksl) + {0,1} of each group.
    const int rr = ((tid >> 3) & 1) * 8 + ((tid >> 4) & 1) * 4 + ((tid >> 5) & 1) * 2;
    const int wbase = wv * 576 + rr * 9 + c;     // + g*144 ; rows rr, rr+1

    const int r_out = tid >> 3;                  // output row (tail phase)
    const size_t BD = (size_t)Bb * Dk;
    const size_t oidx = (size_t)r_out * Dk + e0 + c;
    const int rbase = r_out * 9 + c;             // + wv*576 per partial

    const bool hi3 = (tid & 8)  != 0;
    const bool hi4 = (tid & 16) != 0;
    const bool hi5 = (tid & 32) != 0;

    for (int t = 0; t < Tt; ++t) {
        const float* hb = hbuf + (size_t)t * BD;
        float* hg = hbuf + (size_t)(t + 1) * BD;   // gate in, h_new out
        float* xo = out  + (size_t)t * BD;         // xw in, out_t out
        const float* zt = z + (size_t)t * BD;

        // Prefetch tail operands (block-private; hidden under dot phase).
        float gv = hg[oidx];
        float xv = xo[oidx];
        float zv = zt[oidx];

#pragma unroll 1
        for (int g = 0; g < 4; ++g) {
            // 16 rows x 32-wide k-slice partial dots.
            float acc[16];
            const float* hp = hb + (size_t)(g * 16) * Dk + k0;
#pragma unroll
            for (int r = 0; r < 16; ++r) {
                const float* hr = hp + (size_t)r * Dk;
                float4 h0 = *(const float4*)(hr + 0);
                float4 h1 = *(const float4*)(hr + 4);
                float4 h2 = *(const float4*)(hr + 8);
                float4 h3 = *(const float4*)(hr + 12);
                float4 h4 = *(const float4*)(hr + 16);
                float4 h5 = *(const float4*)(hr + 20);
                float4 h6 = *(const float4*)(hr + 24);
                float4 h7 = *(const float4*)(hr + 28);
                float s0 = 0.f, s1 = 0.f;
                s0 = fmaf(h0.x, w[0], s0);  s1 = fmaf(h0.y, w[1], s1);
                s0 = fmaf(h0.z, w[2], s0);  s1 = fmaf(h0.w, w[3], s1);
                s0 = fmaf(h1.x, w[4], s0);  s1 = fmaf(h1.y, w[5], s1);
                s0 = fmaf(h1.z, w[6], s0);  s1 = fmaf(h1.w, w[7], s1);
                s0 = fmaf(h2.x, w[8], s0);  s1 = fmaf(h2.y, w[9], s1);
                s0 = fmaf(h2.z, w[10], s0); s1 = fmaf(h2.w, w[11], s1);
                s0 = fmaf(h3.x, w[12], s0); s1 = fmaf(h3.y, w[13], s1);
                s0 = fmaf(h3.z, w[14], s0); s1 = fmaf(h3.w, w[15], s1);
                s0 = fmaf(h4.x, w[16], s0); s1 = fmaf(h4.y, w[17], s1);
                s0 = fmaf(h4.z, w[18], s0); s1 = fmaf(h4.w, w[19], s1);
                s0 = fmaf(h5.x, w[20], s0); s1 = fmaf(h5.y, w[21], s1);
                s0 = fmaf(h5.z, w[22], s0); s1 = fmaf(h5.w, w[23], s1);
                s0 = fmaf(h6.x, w[24], s0); s1 = fmaf(h6.y, w[25], s1);
                s0 = fmaf(h6.z, w[26], s0); s1 = fmaf(h6.w, w[27], s1);
                s0 = fmaf(h7.x, w[28], s0); s1 = fmaf(h7.y, w[29], s1);
                s0 = fmaf(h7.z, w[30], s0); s1 = fmaf(h7.w, w[31], s1);
                acc[r] = s0 + s1;
            }

            // Reduce-scatter across ks-local lane bits (8/16/32).
            float t8[8];
#pragma unroll
            for (int j = 0; j < 8; ++j) {
                float send = hi3 ? acc[j] : acc[j + 8];
                float recv = __shfl_xor(send, 8);
                t8[j] = (hi3 ? acc[j + 8] : acc[j]) + recv;
            }
            float t4[4];
#pragma unroll
            for (int j = 0; j < 4; ++j) {
                float send = hi4 ? t8[j] : t8[j + 4];
                float recv = __shfl_xor(send, 16);
                t4[j] = (hi4 ? t8[j + 4] : t8[j]) + recv;
            }
            float t2[2];
#pragma unroll
            for (int j = 0; j < 2; ++j) {
                float send = hi5 ? t4[j] : t4[j + 2];
                float recv = __shfl_xor(send, 32);
                t2[j] = (hi5 ? t4[j + 2] : t4[j]) + recv;
            }

            red[wbase + g * 144]     = t2[0];
            red[wbase + g * 144 + 9] = t2[1];
        }
        __syncthreads();

        // Combine the 8 wave-level partials for this thread's (r_out, c).
        float s = 0.f;
#pragma unroll
        for (int v = 0; v < 8; ++v)
            s += red[v * 576 + rbase];

        float pre = xv + s * gv;
        float hn = tanhf(pre);
        float sz = zv / (1.0f + expf(-zv));
        hg[oidx] = hn;
        xo[oidx] = hn * sz;

        if (t + 1 < Tt) grid.sync();
    }
}

// ------------------------------- launch ------------------------------------
extern "C" void kernel_launch(void* const* d_in, const int* in_sizes, int n_in,
                              void* d_out, int out_size, void* d_ws, size_t ws_size,
                              hipStream_t stream) {
    const float* x    = (const float*)d_in[0];
    const float* z    = (const float*)d_in[1];
    const float* h0   = (const float*)d_in[2];
    const float* Wx   = (const float*)d_in[3];
    const float* Wh   = (const float*)d_in[4];
    const float* Wg   = (const float*)d_in[5];
    const float* bias = (const float*)d_in[6];

    float* out  = (float*)d_out;                      // [T,B,D]
    float* hbuf = out + (size_t)Tt * Bb * Dk;         // [T+1,B,D]

    float* ws    = (float*)d_ws;
    float* u     = ws;          // 2048
    float* v     = ws + 2048;   // 2048
    float* tmp   = ws + 4096;   // 2048
    float* scale = ws + 6144;   // 1

    const size_t BD = (size_t)Bb * Dk;

    // h[0] = h0
    hipMemcpyAsync(hbuf, h0, BD * sizeof(float), hipMemcpyDeviceToDevice, stream);

    // spectral norm scale
    k_rng<<<1, 256, 0, stream>>>(u);
    float* uc = u;
    float* ut = tmp;
    for (int it = 0; it < 3; ++it) {
        k_matvec_T<<<8, 256, 0, stream>>>(Wh, uc, v);
        k_normalize<<<1, 256, 0, stream>>>(v);
        k_matvec_N<<<2048, 256, 0, stream>>>(Wh, v, ut);
        if (it < 2) {
            k_normalize<<<1, 256, 0, stream>>>(ut);
            float* t2 = uc; uc = ut; ut = t2;
        }
    }
    k_sigma<<<1, 256, 0, stream>>>(ut, scale);

    // fused input projections: xw -> out[t] slots, gate -> h[t+1] slots
    dim3 gg(Mrows / 128, Dk / 128);
    k_dualgemm<<<gg, 256, 0, stream>>>(x, Wx, Wg, bias, out, hbuf + BD);

    // persistent cooperative recurrence; verified-safe launch with fallback
    bool coop_done = false;
    {
        int maxActive = 0;
        hipError_t oe = hipOccupancyMaxActiveBlocksPerMultiprocessor(
            &maxActive, k_recur, 512, 0);
        if (oe == hipSuccess && maxActive >= 1) {
            const float* aWh = Wh;
            const float* aSc = scale;
            const float* aZ  = z;
            float* aOut = out;
            float* aH   = hbuf;
            void* kargs[] = {(void*)&aWh, (void*)&aSc, (void*)&aZ,
                             (void*)&aOut, (void*)&aH};
            hipError_t le = hipLaunchCooperativeKernel(
                k_recur, dim3(256), dim3(512), kargs, 0, stream);
            coop_done = (le == hipSuccess);
        }
    }
    if (!coop_done) {
        dim3 gs(Dk / 32, Bb / 32);
        for (int t = 0; t < Tt; ++t) {
            k_step<<<gs, 256, 0, stream>>>(Wh, scale,
                                           z + (size_t)t * BD,
                                           out + (size_t)t * BD,
                                           hbuf + (size_t)t * BD,
                                           hbuf + (size_t)(t + 1) * BD);
        }
    }
}